// Round 15
// baseline (96.882 us; speedup 1.0000x reference)
//
#include <hip/hip_runtime.h>

typedef __attribute__((ext_vector_type(4))) float f32x4;
typedef __attribute__((ext_vector_type(8))) _Float16 f16x8;
typedef __attribute__((ext_vector_type(2))) __fp16 fp16x2_raw;
typedef __attribute__((ext_vector_type(4))) unsigned int u32x4;
typedef __attribute__((ext_vector_type(2))) unsigned int u32x2;

#define MFMA_F16(a, b, c) __builtin_amdgcn_mfma_f32_16x16x32_f16((a), (b), (c), 0, 0, 0)

__device__ __forceinline__ unsigned int pkrtz(float a, float b) {
  union { fp16x2_raw h; unsigned int u; } v;
  v.h = __builtin_amdgcn_cvt_pkrtz(a, b);
  return v.u;
}

// native 2^x (hardware v_exp_f32); exp2f would lower to the OCML libcall (~12 VALU)
__device__ __forceinline__ float fexp2(float x) {
#if __has_builtin(__builtin_amdgcn_exp2f)
  return __builtin_amdgcn_exp2f(x);
#else
  float r;
  asm("v_exp_f32 %0, %1" : "=v"(r) : "v"(x));
  return r;
#endif
}
// native sin/cos of (2*pi*x) -- hardware v_sin/v_cos take REVOLUTIONS
__device__ __forceinline__ float fsin_rev(float x) {
#if __has_builtin(__builtin_amdgcn_sinf)
  return __builtin_amdgcn_sinf(x);
#else
  float r; asm("v_sin_f32 %0, %1" : "=v"(r) : "v"(x)); return r;
#endif
}
__device__ __forceinline__ float fcos_rev(float x) {
#if __has_builtin(__builtin_amdgcn_cosf)
  return __builtin_amdgcn_cosf(x);
#else
  float r; asm("v_cos_f32 %0, %1" : "=v"(r) : "v"(x)); return r;
#endif
}

typedef const __attribute__((address_space(1))) unsigned int ga_u32_t;
typedef __attribute__((address_space(3))) unsigned int ls_u32_t;
__device__ __forceinline__ void gload16(const void* g, void* l) {
  __builtin_amdgcn_global_load_lds((ga_u32_t*)g, (ls_u32_t*)l, 16, 0, 0);
}

// inverse of LDS map addr_phys = (r*64 + ch*16) ^ ((r&7)<<4): given (seg,lane)
// covering phys = seg*1024 + lane*16, return logical row r and 16B-chunk ch.
__device__ __forceinline__ void inv_swz64(int seg, int lane, int& r, int& ch) {
  int r_hi = seg * 8 + (lane >> 3);               // r >> 1
  int r0 = ((lane >> 2) & 1) ^ ((r_hi >> 1) & 1); // phys_b6 ^ r2
  r = (r_hi << 1) | r0;
  ch = (lane & 3) ^ (r & 3);
}

// ---------- prep (merged): x f32->fp16 (blocks 0..4095) + weight transposes ----------
__global__ __launch_bounds__(256)
void k_prep(const float* __restrict__ x, _Float16* __restrict__ xh,
            const float* __restrict__ wq, _Float16* __restrict__ wqT,
            const float* __restrict__ wp, _Float16* __restrict__ wpT) {
  const int b = blockIdx.x;
  const int tid = threadIdx.x;
  if (b < 4096) {
    int i = (b * 256 + tid) * 4;
    f32x4 v = *(const f32x4*)(x + i);
    u32x2 p;
    p.x = pkrtz(v[0], v[1]);
    p.y = pkrtz(v[2], v[3]);
    *(u32x2*)(xh + i) = p;
    return;
  }
  __shared__ float t[64][65];
  const int wb = b - 4096;          // 0..255
  const int bx = wb & 31, by = wb >> 5;
  const float* in = (bx < 24) ? wq : wp;
  _Float16* out = (bx < 24) ? wqT : wpT;
  const int N = (bx < 24) ? 1536 : 512;
  const int bn = ((bx < 24) ? bx : bx - 24) * 64, bk = by * 64;
  #pragma unroll
  for (int it = 0; it < 16; ++it) {
    int idx = it * 256 + tid;
    int kk = idx >> 6, nn = idx & 63;
    t[kk][nn] = in[(bk + kk) * N + bn + nn];
  }
  __syncthreads();
  #pragma unroll
  for (int it = 0; it < 16; ++it) {
    int idx = it * 256 + tid;
    int nn = idx >> 6, kk = idx & 63;
    out[(bn + nn) * 512 + bk + kk] = (_Float16)t[kk][nn];
  }
}

// ---------- GEMM1: qkv = xh @ w_qkv (all staging via global_load_lds), fused RoPE ----------
__global__ __launch_bounds__(256, 3)
void k_gemm_qkv(const _Float16* __restrict__ xh,
                const _Float16* __restrict__ wT,
                const int* __restrict__ pos_h,
                const int* __restrict__ pos_w,
                _Float16* __restrict__ qh,
                _Float16* __restrict__ kh,
                _Float16* __restrict__ vT) {
  __shared__ char As[8192], Bs[8192];
  const int tid = threadIdx.x;
  const int lane = tid & 63, w = tid >> 6;
  const int lr = lane & 15, g = lane >> 4;
  const int m0 = blockIdx.y * 128;
  const int n0 = blockIdx.x * 128;
  const int wr = w >> 1, wc = w & 1;

  // hoisted gload_lds source addresses (pre-inverse-swizzled)
  const _Float16* asrc[2];
  const _Float16* bsrc[2];
  #pragma unroll
  for (int c = 0; c < 2; ++c) {
    int seg = w * 2 + c, r, ch;
    inv_swz64(seg, lane, r, ch);
    asrc[c] = xh + (size_t)(m0 + r) * 512 + ch * 8;
    bsrc[c] = wT + (size_t)(n0 + r) * 512 + ch * 8;
  }

  f32x4 acc[4][4];
  #pragma unroll
  for (int i = 0; i < 4; ++i)
    #pragma unroll
    for (int j = 0; j < 4; ++j) acc[i][j] = (f32x4){0.f, 0.f, 0.f, 0.f};

  for (int kt = 0; kt < 16; ++kt) {
    const int k0 = kt * 32;
    __syncthreads();
    #pragma unroll
    for (int c = 0; c < 2; ++c) {
      gload16(asrc[c] + k0, As + (w * 2 + c) * 1024);
      gload16(bsrc[c] + k0, Bs + (w * 2 + c) * 1024);
    }
    __syncthreads();

    f16x8 af[4], bf[4];
    #pragma unroll
    for (int mi = 0; mi < 4; ++mi) {
      int r = 64 * wr + 16 * mi + lr;
      af[mi] = *(const f16x8*)(As + (((r << 6) + (g << 4)) ^ ((r & 7) << 4)));
    }
    #pragma unroll
    for (int nj = 0; nj < 4; ++nj) {
      int r = 64 * wc + 16 * nj + lr;
      bf[nj] = *(const f16x8*)(Bs + (((r << 6) + (g << 4)) ^ ((r & 7) << 4)));
    }
    __builtin_amdgcn_s_setprio(1);
    #pragma unroll
    for (int mi = 0; mi < 4; ++mi)
      #pragma unroll
      for (int nj = 0; nj < 4; ++nj)
        acc[mi][nj] = MFMA_F16(af[mi], bf[nj], acc[mi][nj]);
    __builtin_amdgcn_s_setprio(0);
  }

  // epilogue: RoPE (q,k) with native trig + permuted-transpose write (v)
  #pragma unroll
  for (int mi = 0; mi < 4; ++mi) {
    const int r0f = m0 + 64 * wr + 16 * mi + 4 * g;
    const int n = r0f >> 11;
    const int t = r0f & 2047;
    #pragma unroll
    for (int nj = 0; nj < 4; ++nj) {
      const int c = n0 + 64 * wc + 16 * nj + lr;
      const int mat = c >> 9;          // 0=q 1=k 2=v
      const int hh = (c >> 6) & 7;
      const int dh = c & 63;
      f32x4 v = acc[mi][nj];
      if (mat == 2) {
        // permute s within 32-block: s=16a+4b+c -> kpos=8b+4a+c (here t%4==0)
        int tperm = (t & ~31) + 8 * ((t >> 2) & 3) + 4 * ((t >> 4) & 1);
        u32x2 pk2;
        pk2.x = pkrtz(v[0], v[1]);
        pk2.y = pkrtz(v[2], v[3]);
        *(u32x2*)(vT + (size_t)((n * 8 + hh) * 64 + dh) * 2048 + tperm) = pk2;
      } else {
        const int p = (dh & 31) >> 1;
        // freq in REVOLUTIONS: theta^(-p/16) / (2*pi)
        const float freq_rev = fexp2((float)p * -0.8304820237218405f) * 0.15915494309189535f;
        const int odd = lane & 1;
        const int* posArr = (dh < 32) ? pos_h : pos_w;
        _Float16* dst = mat ? kh : qh;
        // q: fold 1/sqrt(64) AND log2(e) (softmax uses exp2)
        const float scale = mat ? 1.0f : 0.125f * 1.44269504088896f;
        #pragma unroll
        for (int i = 0; i < 4; ++i) {
          float val = v[i];
          float oth = __shfl_xor(val, 1);
          float ar = (float)posArr[t + i] * freq_rev;
          ar = ar - floorf(ar);                // reduce to [0,1) revolutions
          float sv = fsin_rev(ar);
          float cv = fcos_rev(ar);
          float x1 = odd ? oth : val;
          float x2 = odd ? val : oth;
          float res = odd ? (x1 * sv + x2 * cv) : (x1 * cv - x2 * sv);
          dst[(size_t)((n * 8 + hh) * 2048 + t + i) * 64 + dh] = (_Float16)(res * scale);
        }
      }
    }
  }
}

// ---------- flash attention: KV-split x2, fixed-M (combine is a plain sum) ----------
// grid 1024: bid = [nh_hi(2) | qt(4) | sp(1) | nh_lo(3)]
__global__ __launch_bounds__(256, 3)
void k_attn(const _Float16* __restrict__ qh,
            const _Float16* __restrict__ kh,
            const _Float16* __restrict__ vp,
            _Float16* __restrict__ opart,   // [2][65536][64] UNnormalized fp16
            float* __restrict__ ml) {       // [2][65536] l-sums
  __shared__ char Ks[2][16384];  // dbuf: [2 sub][64 s][64 dh] f16, pre-swz ^((s&7)<<4)
  __shared__ char Vs[16384];     // single-buffer: staged at barrier A for CURRENT phase
  const int tid = threadIdx.x, lane = tid & 63, w = tid >> 6;
  const int lr = lane & 15, g = lane >> 4;
  const int bid = blockIdx.x;
  const int sp = (bid >> 3) & 1;
  const int qt = (bid >> 4) & 15;
  const int nh = (bid & 7) + 8 * (bid >> 8);

  // Q fragments (B-operand: col=q=lr, k=dh)
  f16x8 qf[2][2];
  const _Float16* qbase = qh + ((size_t)nh * 2048 + qt * 128 + w * 32) * 64;
  #pragma unroll
  for (int mi = 0; mi < 2; ++mi)
    #pragma unroll
    for (int kg = 0; kg < 2; ++kg)
      qf[mi][kg] = *(const f16x8*)(qbase + (16 * mi + lr) * 64 + kg * 32 + g * 8);

  // all-ones A fragment for the l-accumulating MFMA
  f16x8 ones;
  #pragma unroll
  for (int i = 0; i < 8; ++i) ones[i] = (_Float16)1.0f;

  f32x4 oacc[2][4];
  f32x4 lacc4[2];
  #pragma unroll
  for (int mi = 0; mi < 2; ++mi) {
    lacc4[mi] = (f32x4){0.f, 0.f, 0.f, 0.f};
    #pragma unroll
    for (int nf = 0; nf < 4; ++nf) oacc[mi][nf] = (f32x4){0.f, 0.f, 0.f, 0.f};
  }

  const _Float16* kb = kh + (size_t)nh * 2048 * 64;
  const _Float16* vb = vp + (size_t)nh * 64 * 2048;

  // hoisted staging addresses (phase-invariant part)
  const int rr = lane >> 3, cc = lane & 7;
  const _Float16* ksrc[2];
  const _Float16* vsrc[2];
  #pragma unroll
  for (int c = 0; c < 2; ++c) {
    int seg = w * 2 + c;
    int r = seg * 8 + rr;
    ksrc[c] = kb + (size_t)r * 64 + ((cc ^ (r & 7)) << 3);
    vsrc[c] = vb + (size_t)r * 2048 + ((cc ^ (r & 7)) << 3);
  }
  auto stageK = [&](int b, int kt2) {   // 4 loads/wave (kt2 absolute, 128-s units)
    #pragma unroll
    for (int h = 0; h < 2; ++h) {
      int kt = kt2 * 2 + h;
      #pragma unroll
      for (int c = 0; c < 2; ++c)
        gload16(ksrc[c] + (size_t)kt * 4096, Ks[b] + h * 8192 + (w * 2 + c) * 1024);
    }
  };
  auto stageV = [&](int kt2) {          // 4 loads/wave, CURRENT phase, single buffer
    #pragma unroll
    for (int h = 0; h < 2; ++h) {
      int kt = kt2 * 2 + h;
      #pragma unroll
      for (int c = 0; c < 2; ++c)
        gload16(vsrc[c] + (size_t)kt * 64, Vs + h * 8192 + (w * 2 + c) * 1024);
    }
  };

  const int kt0 = sp * 8;   // this split's 8 phases (of 16)
  stageK(0, kt0);           // prologue

  const f32x4 cinit = (f32x4){-8.f, -8.f, -8.f, -8.f};  // fixed-M bias, free in C

  for (int k2 = 0; k2 < 8; ++k2) {
    const int cur = k2 & 1;
    asm volatile("" ::: "memory");
    __builtin_amdgcn_s_barrier();          // A: all done reading Ks[cur^1] and Vs
    stageV(kt0 + k2);                      // V for CURRENT phase (4 loads)
    if (k2 + 1 < 8) {
      stageK(cur ^ 1, kt0 + k2 + 1);       // prefetch next K (4 loads)
      // queue: K-cur(4, prev iter), V-cur(4), K-next(4) -> wait leaves K-next
      asm volatile("s_waitcnt vmcnt(4)" ::: "memory");
    } else {
      asm volatile("s_waitcnt vmcnt(0)" ::: "memory");
    }
    __builtin_amdgcn_s_barrier();          // B: K-cur + V-cur visible to all
    asm volatile("" ::: "memory");

    // S^T = K Q^T for both sub-tiles
    f32x4 sacc[2][2][4];
    #pragma unroll
    for (int h = 0; h < 2; ++h)
      #pragma unroll
      for (int mi = 0; mi < 2; ++mi)
        #pragma unroll
        for (int sj = 0; sj < 4; ++sj) sacc[h][mi][sj] = cinit;

    __builtin_amdgcn_s_setprio(1);
    #pragma unroll
    for (int h = 0; h < 2; ++h) {
      const char* Kb = Ks[cur] + h * 8192;
      #pragma unroll
      for (int sj = 0; sj < 4; ++sj) {
        int s = sj * 16 + lr;
        int rb = s << 7, sw = (s & 7) << 4;
        #pragma unroll
        for (int kg = 0; kg < 2; ++kg) {
          f16x8 kf = *(const f16x8*)(Kb + ((rb + (kg << 6) + (g << 4)) ^ sw));
          sacc[h][0][sj] = MFMA_F16(kf, qf[0][kg], sacc[h][0][sj]);
          sacc[h][1][sj] = MFMA_F16(kf, qf[1][kg], sacc[h][1][sj]);
        }
      }
    }
    __builtin_amdgcn_s_setprio(0);

    // per sub-tile: fixed-M softmax (native v_exp) then PV; l via ones-MFMA
    #pragma unroll
    for (int h = 0; h < 2; ++h) {
      const char* Vb = Vs + h * 8192;
      #pragma unroll
      for (int mi = 0; mi < 2; ++mi)
        #pragma unroll
        for (int sj = 0; sj < 4; ++sj) {
          sacc[h][mi][sj][0] = fexp2(sacc[h][mi][sj][0]);
          sacc[h][mi][sj][1] = fexp2(sacc[h][mi][sj][1]);
          sacc[h][mi][sj][2] = fexp2(sacc[h][mi][sj][2]);
          sacc[h][mi][sj][3] = fexp2(sacc[h][mi][sj][3]);
        }
      __builtin_amdgcn_s_setprio(1);
      #pragma unroll
      for (int t = 0; t < 2; ++t) {
        f16x8 vf[4];
        #pragma unroll
        for (int nf = 0; nf < 4; ++nf) {
          int dh = 16 * nf + lr;
          vf[nf] = *(const f16x8*)(Vb + (((dh << 7) + (t << 6) + (g << 4)) ^ ((dh & 7) << 4)));
        }
        #pragma unroll
        for (int mi = 0; mi < 2; ++mi) {
          union { unsigned int u[4]; f16x8 h; } pb;
          pb.u[0] = pkrtz(sacc[h][mi][2 * t][0], sacc[h][mi][2 * t][1]);
          pb.u[1] = pkrtz(sacc[h][mi][2 * t][2], sacc[h][mi][2 * t][3]);
          pb.u[2] = pkrtz(sacc[h][mi][2 * t + 1][0], sacc[h][mi][2 * t + 1][1]);
          pb.u[3] = pkrtz(sacc[h][mi][2 * t + 1][2], sacc[h][mi][2 * t + 1][3]);
          lacc4[mi] = MFMA_F16(ones, pb.h, lacc4[mi]);   // l[q] += sum P (matrix pipe)
          #pragma unroll
          for (int nf = 0; nf < 4; ++nf)
            oacc[mi][nf] = MFMA_F16(vf[nf], pb.h, oacc[mi][nf]);
        }
      }
      __builtin_amdgcn_s_setprio(0);
    }
  }

  // epilogue: UNnormalized partial O (fp16) + l per row (fixed-M => sums combine)
  const int ridb = nh * 2048 + qt * 128 + w * 32;
  #pragma unroll
  for (int mi = 0; mi < 2; ++mi) {
    const int rid = ridb + 16 * mi + lr;
    _Float16* orow = opart + ((size_t)sp * 65536 + rid) * 64;
    #pragma unroll
    for (int nf = 0; nf < 4; ++nf) {
      u32x2 pk2;
      pk2.x = pkrtz(oacc[mi][nf][0], oacc[mi][nf][1]);
      pk2.y = pkrtz(oacc[mi][nf][2], oacc[mi][nf][3]);
      *(u32x2*)(orow + 16 * nf + 4 * g) = pk2;
    }
    if (g == 0) ml[(size_t)sp * 65536 + rid] = lacc4[mi][0];
  }
}

// ---------- combine: o = (O0+O1)/(l0+l1) -> o_flat fp16 [8192][512] ----------
__global__ __launch_bounds__(256)
void k_combine(const _Float16* __restrict__ opart,
               const float* __restrict__ ml,
               _Float16* __restrict__ o_flat) {
  int t = blockIdx.x * 256 + threadIdx.x;       // 524288 threads
  int rid = t >> 3, c8 = (t & 7) * 8;
  float inv = 1.0f / (ml[rid] + ml[65536 + rid]);
  union { u32x4 u; _Float16 h[8]; } o0, o1, r;
  o0.u = *(const u32x4*)(opart + (size_t)rid * 64 + c8);
  o1.u = *(const u32x4*)(opart + ((size_t)65536 + rid) * 64 + c8);
  #pragma unroll
  for (int i = 0; i < 4; ++i) {
    float lo = ((float)o0.h[2 * i]     + (float)o1.h[2 * i]) * inv;
    float hi = ((float)o0.h[2 * i + 1] + (float)o1.h[2 * i + 1]) * inv;
    ((unsigned int*)&r.u)[i] = pkrtz(lo, hi);
  }
  int nh = rid >> 11, row = rid & 2047;
  int n = nh >> 3, h = nh & 7;
  *(u32x4*)(o_flat + (size_t)(n * 2048 + row) * 512 + h * 64 + c8) = r.u;
}

// ---------- GEMM3: out = o @ w_proj + b (fp16 -> f32, gload_lds staging) ----------
__global__ __launch_bounds__(256, 3)
void k_gemm_proj(const _Float16* __restrict__ o_flat,
                 const _Float16* __restrict__ wpT,
                 const float* __restrict__ bias,
                 float* __restrict__ out) {
  __shared__ char As[8192], Bs[8192];
  const int tid = threadIdx.x;
  const int lane = tid & 63, w = tid >> 6;
  const int lr = lane & 15, g = lane >> 4;
  const int m0 = blockIdx.y * 128;
  const int n0 = blockIdx.x * 128;
  const int wr = w >> 1, wc = w & 1;

  const _Float16* asrc[2];
  const _Float16* bsrc[2];
  #pragma unroll
  for (int c = 0; c < 2; ++c) {
    int seg = w * 2 + c, r, ch;
    inv_swz64(seg, lane, r, ch);
    asrc[c] = o_flat + (size_t)(m0 + r) * 512 + ch * 8;
    bsrc[c] = wpT + (size_t)(n0 + r) * 512 + ch * 8;
  }

  f32x4 acc[4][4];
  #pragma unroll
  for (int i = 0; i < 4; ++i)
    #pragma unroll
    for (int j = 0; j < 4; ++j) acc[i][j] = (f32x4){0.f, 0.f, 0.f, 0.f};

  for (int kt = 0; kt < 16; ++kt) {
    const int k0 = kt * 32;
    __syncthreads();
    #pragma unroll
    for (int c = 0; c < 2; ++c) {
      gload16(asrc[c] + k0, As + (w * 2 + c) * 1024);
      gload16(bsrc[c] + k0, Bs + (w * 2 + c) * 1024);
    }
    __syncthreads();

    f16x8 af[4], bf[4];
    #pragma unroll
    for (int mi = 0; mi < 4; ++mi) {
      int r = 64 * wr + 16 * mi + lr;
      af[mi] = *(const f16x8*)(As + (((r << 6) + (g << 4)) ^ ((r & 7) << 4)));
    }
    #pragma unroll
    for (int nj = 0; nj < 4; ++nj) {
      int r = 64 * wc + 16 * nj + lr;
      bf[nj] = *(const f16x8*)(Bs + (((r << 6) + (g << 4)) ^ ((r & 7) << 4)));
    }
    __builtin_amdgcn_s_setprio(1);
    #pragma unroll
    for (int mi = 0; mi < 4; ++mi)
      #pragma unroll
      for (int nj = 0; nj < 4; ++nj)
        acc[mi][nj] = MFMA_F16(af[mi], bf[nj], acc[mi][nj]);
    __builtin_amdgcn_s_setprio(0);
  }

  #pragma unroll
  for (int mi = 0; mi < 4; ++mi) {
    int r0f = m0 + 64 * wr + 16 * mi + 4 * g;
    #pragma unroll
    for (int nj = 0; nj < 4; ++nj) {
      int c = n0 + 64 * wc + 16 * nj + lr;
      float b = bias[c];
      #pragma unroll
      for (int i = 0; i < 4; ++i)
        out[(size_t)(r0f + i) * 512 + c] = acc[mi][nj][i] + b;
    }
  }
}

extern "C" void kernel_launch(void* const* d_in, const int* in_sizes, int n_in,
                              void* d_out, int out_size, void* d_ws, size_t ws_size,
                              hipStream_t stream) {
  const float* x      = (const float*)d_in[0];
  const int*   pos_h  = (const int*)d_in[1];
  const int*   pos_w  = (const int*)d_in[2];
  const float* w_qkv  = (const float*)d_in[3];
  const float* w_proj = (const float*)d_in[4];
  const float* b_proj = (const float*)d_in[5];
  float* out = (float*)d_out;

  char* ws = (char*)d_ws;
  size_t off = 0;
  auto alloc = [&](size_t bytes) {
    char* p = ws + off;
    off += (bytes + 1023) & ~(size_t)1023;
    return p;
  };
  _Float16* xh     = (_Float16*)alloc((size_t)8192 * 512 * 2);
  _Float16* qh     = (_Float16*)alloc((size_t)32 * 2048 * 64 * 2);
  _Float16* kh     = (_Float16*)alloc((size_t)32 * 2048 * 64 * 2);
  _Float16* vT     = (_Float16*)alloc((size_t)32 * 2048 * 64 * 2);
  _Float16* o_flat = (_Float16*)alloc((size_t)8192 * 512 * 2);
  _Float16* wqT    = (_Float16*)alloc((size_t)1536 * 512 * 2);
  _Float16* wpT    = (_Float16*)alloc((size_t)512 * 512 * 2);
  _Float16* opart  = (_Float16*)alloc((size_t)2 * 65536 * 64 * 2);
  float*    ml     = (float*)alloc((size_t)2 * 65536 * 4);

  hipLaunchKernelGGL(k_prep, dim3(4352), dim3(256), 0, stream,
                     x, xh, w_qkv, wqT, w_proj, wpT);
  hipLaunchKernelGGL(k_gemm_qkv, dim3(12, 64), dim3(256), 0, stream,
                     xh, wqT, pos_h, pos_w, qh, kh, vT);
  hipLaunchKernelGGL(k_attn, dim3(1024), dim3(256), 0, stream, qh, kh, vT, opart, ml);
  hipLaunchKernelGGL(k_combine, dim3(2048), dim3(256), 0, stream, opart, ml, o_flat);
  hipLaunchKernelGGL(k_gemm_proj, dim3(4, 64), dim3(256), 0, stream, o_flat, wpT, b_proj, out);
}

// Round 16
// 89.548 us; speedup vs baseline: 1.0819x; 1.0819x over previous
//
#include <hip/hip_runtime.h>

typedef __attribute__((ext_vector_type(4))) float f32x4;
typedef __attribute__((ext_vector_type(8))) _Float16 f16x8;
typedef __attribute__((ext_vector_type(2))) __fp16 fp16x2_raw;
typedef __attribute__((ext_vector_type(4))) unsigned int u32x4;
typedef __attribute__((ext_vector_type(2))) unsigned int u32x2;

#define MFMA_F16(a, b, c) __builtin_amdgcn_mfma_f32_16x16x32_f16((a), (b), (c), 0, 0, 0)

__device__ __forceinline__ unsigned int pkrtz(float a, float b) {
  union { fp16x2_raw h; unsigned int u; } v;
  v.h = __builtin_amdgcn_cvt_pkrtz(a, b);
  return v.u;
}

// native 2^x (hardware v_exp_f32); exp2f would lower to the OCML libcall (~12 VALU)
__device__ __forceinline__ float fexp2(float x) {
#if __has_builtin(__builtin_amdgcn_exp2f)
  return __builtin_amdgcn_exp2f(x);
#else
  float r;
  asm("v_exp_f32 %0, %1" : "=v"(r) : "v"(x));
  return r;
#endif
}
// native sin/cos of (2*pi*x) -- hardware v_sin/v_cos take REVOLUTIONS
__device__ __forceinline__ float fsin_rev(float x) {
#if __has_builtin(__builtin_amdgcn_sinf)
  return __builtin_amdgcn_sinf(x);
#else
  float r; asm("v_sin_f32 %0, %1" : "=v"(r) : "v"(x)); return r;
#endif
}
__device__ __forceinline__ float fcos_rev(float x) {
#if __has_builtin(__builtin_amdgcn_cosf)
  return __builtin_amdgcn_cosf(x);
#else
  float r; asm("v_cos_f32 %0, %1" : "=v"(r) : "v"(x)); return r;
#endif
}

typedef const __attribute__((address_space(1))) unsigned int ga_u32_t;
typedef __attribute__((address_space(3))) unsigned int ls_u32_t;
__device__ __forceinline__ void gload16(const void* g, void* l) {
  __builtin_amdgcn_global_load_lds((ga_u32_t*)g, (ls_u32_t*)l, 16, 0, 0);
}

// inverse of LDS map addr_phys = (r*64 + ch*16) ^ ((r&7)<<4): given (seg,lane)
// covering phys = seg*1024 + lane*16, return logical row r and 16B-chunk ch.
__device__ __forceinline__ void inv_swz64(int seg, int lane, int& r, int& ch) {
  int r_hi = seg * 8 + (lane >> 3);               // r >> 1
  int r0 = ((lane >> 2) & 1) ^ ((r_hi >> 1) & 1); // phys_b6 ^ r2
  r = (r_hi << 1) | r0;
  ch = (lane & 3) ^ (r & 3);
}

// ---------- prep (merged): x f32->fp16 (blocks 0..4095) + weight transposes ----------
__global__ __launch_bounds__(256)
void k_prep(const float* __restrict__ x, _Float16* __restrict__ xh,
            const float* __restrict__ wq, _Float16* __restrict__ wqT,
            const float* __restrict__ wp, _Float16* __restrict__ wpT) {
  const int b = blockIdx.x;
  const int tid = threadIdx.x;
  if (b < 4096) {
    int i = (b * 256 + tid) * 4;
    f32x4 v = *(const f32x4*)(x + i);
    u32x2 p;
    p.x = pkrtz(v[0], v[1]);
    p.y = pkrtz(v[2], v[3]);
    *(u32x2*)(xh + i) = p;
    return;
  }
  __shared__ float t[64][65];
  const int wb = b - 4096;          // 0..255
  const int bx = wb & 31, by = wb >> 5;
  const float* in = (bx < 24) ? wq : wp;
  _Float16* out = (bx < 24) ? wqT : wpT;
  const int N = (bx < 24) ? 1536 : 512;
  const int bn = ((bx < 24) ? bx : bx - 24) * 64, bk = by * 64;
  #pragma unroll
  for (int it = 0; it < 16; ++it) {
    int idx = it * 256 + tid;
    int kk = idx >> 6, nn = idx & 63;
    t[kk][nn] = in[(bk + kk) * N + bn + nn];
  }
  __syncthreads();
  #pragma unroll
  for (int it = 0; it < 16; ++it) {
    int idx = it * 256 + tid;
    int nn = idx >> 6, kk = idx & 63;
    out[(bn + nn) * 512 + bk + kk] = (_Float16)t[kk][nn];
  }
}

// ---------- GEMM1: qkv = xh @ w_qkv (all staging via global_load_lds), fused RoPE ----------
__global__ __launch_bounds__(256, 3)
void k_gemm_qkv(const _Float16* __restrict__ xh,
                const _Float16* __restrict__ wT,
                const int* __restrict__ pos_h,
                const int* __restrict__ pos_w,
                _Float16* __restrict__ qh,
                _Float16* __restrict__ kh,
                _Float16* __restrict__ vT) {
  __shared__ char As[8192], Bs[8192];
  const int tid = threadIdx.x;
  const int lane = tid & 63, w = tid >> 6;
  const int lr = lane & 15, g = lane >> 4;
  const int m0 = blockIdx.y * 128;
  const int n0 = blockIdx.x * 128;
  const int wr = w >> 1, wc = w & 1;

  // hoisted gload_lds source addresses (pre-inverse-swizzled)
  const _Float16* asrc[2];
  const _Float16* bsrc[2];
  #pragma unroll
  for (int c = 0; c < 2; ++c) {
    int seg = w * 2 + c, r, ch;
    inv_swz64(seg, lane, r, ch);
    asrc[c] = xh + (size_t)(m0 + r) * 512 + ch * 8;
    bsrc[c] = wT + (size_t)(n0 + r) * 512 + ch * 8;
  }

  f32x4 acc[4][4];
  #pragma unroll
  for (int i = 0; i < 4; ++i)
    #pragma unroll
    for (int j = 0; j < 4; ++j) acc[i][j] = (f32x4){0.f, 0.f, 0.f, 0.f};

  for (int kt = 0; kt < 16; ++kt) {
    const int k0 = kt * 32;
    __syncthreads();
    #pragma unroll
    for (int c = 0; c < 2; ++c) {
      gload16(asrc[c] + k0, As + (w * 2 + c) * 1024);
      gload16(bsrc[c] + k0, Bs + (w * 2 + c) * 1024);
    }
    __syncthreads();

    f16x8 af[4], bf[4];
    #pragma unroll
    for (int mi = 0; mi < 4; ++mi) {
      int r = 64 * wr + 16 * mi + lr;
      af[mi] = *(const f16x8*)(As + (((r << 6) + (g << 4)) ^ ((r & 7) << 4)));
    }
    #pragma unroll
    for (int nj = 0; nj < 4; ++nj) {
      int r = 64 * wc + 16 * nj + lr;
      bf[nj] = *(const f16x8*)(Bs + (((r << 6) + (g << 4)) ^ ((r & 7) << 4)));
    }
    __builtin_amdgcn_s_setprio(1);
    #pragma unroll
    for (int mi = 0; mi < 4; ++mi)
      #pragma unroll
      for (int nj = 0; nj < 4; ++nj)
        acc[mi][nj] = MFMA_F16(af[mi], bf[nj], acc[mi][nj]);
    __builtin_amdgcn_s_setprio(0);
  }

  // epilogue: RoPE (q,k) with native trig + permuted-transpose write (v)
  #pragma unroll
  for (int mi = 0; mi < 4; ++mi) {
    const int r0f = m0 + 64 * wr + 16 * mi + 4 * g;
    const int n = r0f >> 11;
    const int t = r0f & 2047;
    #pragma unroll
    for (int nj = 0; nj < 4; ++nj) {
      const int c = n0 + 64 * wc + 16 * nj + lr;
      const int mat = c >> 9;          // 0=q 1=k 2=v
      const int hh = (c >> 6) & 7;
      const int dh = c & 63;
      f32x4 v = acc[mi][nj];
      if (mat == 2) {
        // permute s within 32-block: s=16a+4b+c -> kpos=8b+4a+c (here t%4==0)
        int tperm = (t & ~31) + 8 * ((t >> 2) & 3) + 4 * ((t >> 4) & 1);
        u32x2 pk2;
        pk2.x = pkrtz(v[0], v[1]);
        pk2.y = pkrtz(v[2], v[3]);
        *(u32x2*)(vT + (size_t)((n * 8 + hh) * 64 + dh) * 2048 + tperm) = pk2;
      } else {
        const int p = (dh & 31) >> 1;
        // freq in REVOLUTIONS: theta^(-p/16) / (2*pi)
        const float freq_rev = fexp2((float)p * -0.8304820237218405f) * 0.15915494309189535f;
        const int odd = lane & 1;
        const int* posArr = (dh < 32) ? pos_h : pos_w;
        _Float16* dst = mat ? kh : qh;
        // q: fold 1/sqrt(64) AND log2(e) (softmax uses exp2)
        const float scale = mat ? 1.0f : 0.125f * 1.44269504088896f;
        #pragma unroll
        for (int i = 0; i < 4; ++i) {
          float val = v[i];
          float oth = __shfl_xor(val, 1);
          float ar = (float)posArr[t + i] * freq_rev;
          ar = ar - floorf(ar);                // reduce to [0,1) revolutions
          float sv = fsin_rev(ar);
          float cv = fcos_rev(ar);
          float x1 = odd ? oth : val;
          float x2 = odd ? val : oth;
          float res = odd ? (x1 * sv + x2 * cv) : (x1 * cv - x2 * sv);
          dst[(size_t)((n * 8 + hh) * 2048 + t + i) * 64 + dh] = (_Float16)(res * scale);
        }
      }
    }
  }
}

// ---------- flash attention: 128-wide phases, K dbuf + V single-buffer (48KB LDS) ----------
// grid 512 (1D, XCD-aware: nh = (bid&7)+8*(bid>>7), qt = (bid>>3)&15)
__global__ __launch_bounds__(256, 3)
void k_attn(const _Float16* __restrict__ qh,
            const _Float16* __restrict__ kh,
            const _Float16* __restrict__ vp,
            _Float16* __restrict__ o_flat) {
  __shared__ char Ks[2][16384];  // dbuf: [2 sub][64 s][64 dh] f16, pre-swz ^((s&7)<<4)
  __shared__ char Vs[16384];     // single-buffer: staged at barrier A for CURRENT phase
  const int tid = threadIdx.x, lane = tid & 63, w = tid >> 6;
  const int lr = lane & 15, g = lane >> 4;
  const int bid = blockIdx.x;
  const int qt = (bid >> 3) & 15;
  const int nh = (bid & 7) + 8 * (bid >> 7);

  // Q fragments (B-operand: col=q=lr, k=dh)
  f16x8 qf[2][2];
  const _Float16* qbase = qh + ((size_t)nh * 2048 + qt * 128 + w * 32) * 64;
  #pragma unroll
  for (int mi = 0; mi < 2; ++mi)
    #pragma unroll
    for (int kg = 0; kg < 2; ++kg)
      qf[mi][kg] = *(const f16x8*)(qbase + (16 * mi + lr) * 64 + kg * 32 + g * 8);

  // all-ones A fragment for the l-accumulating MFMA
  f16x8 ones;
  #pragma unroll
  for (int i = 0; i < 8; ++i) ones[i] = (_Float16)1.0f;

  f32x4 oacc[2][4];
  f32x4 lacc4[2];
  #pragma unroll
  for (int mi = 0; mi < 2; ++mi) {
    lacc4[mi] = (f32x4){0.f, 0.f, 0.f, 0.f};
    #pragma unroll
    for (int nf = 0; nf < 4; ++nf) oacc[mi][nf] = (f32x4){0.f, 0.f, 0.f, 0.f};
  }

  const _Float16* kb = kh + (size_t)nh * 2048 * 64;
  const _Float16* vb = vp + (size_t)nh * 64 * 2048;

  // hoisted staging addresses (phase-invariant part)
  const int rr = lane >> 3, cc = lane & 7;
  const _Float16* ksrc[2];
  const _Float16* vsrc[2];
  #pragma unroll
  for (int c = 0; c < 2; ++c) {
    int seg = w * 2 + c;
    int r = seg * 8 + rr;
    ksrc[c] = kb + (size_t)r * 64 + ((cc ^ (r & 7)) << 3);
    vsrc[c] = vb + (size_t)r * 2048 + ((cc ^ (r & 7)) << 3);
  }
  auto stageK = [&](int b, int kt2) {   // 4 loads/wave
    #pragma unroll
    for (int h = 0; h < 2; ++h) {
      int kt = kt2 * 2 + h;
      #pragma unroll
      for (int c = 0; c < 2; ++c)
        gload16(ksrc[c] + (size_t)kt * 4096, Ks[b] + h * 8192 + (w * 2 + c) * 1024);
    }
  };
  auto stageV = [&](int kt2) {          // 4 loads/wave, CURRENT phase, single buffer
    #pragma unroll
    for (int h = 0; h < 2; ++h) {
      int kt = kt2 * 2 + h;
      #pragma unroll
      for (int c = 0; c < 2; ++c)
        gload16(vsrc[c] + (size_t)kt * 64, Vs + h * 8192 + (w * 2 + c) * 1024);
    }
  };

  stageK(0, 0);  // prologue

  const f32x4 cinit = (f32x4){-8.f, -8.f, -8.f, -8.f};  // fixed-M bias, free in C

  for (int kt2 = 0; kt2 < 16; ++kt2) {
    const int cur = kt2 & 1;
    asm volatile("" ::: "memory");
    __builtin_amdgcn_s_barrier();          // A: all done reading Ks[cur^1] and Vs
    stageV(kt2);                           // V for CURRENT phase (4 loads)
    if (kt2 + 1 < 16) {
      stageK(cur ^ 1, kt2 + 1);            // prefetch next K (4 loads)
      // queue: K-cur(4, prev iter), V-cur(4), K-next(4) -> wait leaves K-next
      asm volatile("s_waitcnt vmcnt(4)" ::: "memory");
    } else {
      asm volatile("s_waitcnt vmcnt(0)" ::: "memory");
    }
    __builtin_amdgcn_s_barrier();          // B: K-cur + V-cur visible to all
    asm volatile("" ::: "memory");

    // S^T = K Q^T for both sub-tiles
    f32x4 sacc[2][2][4];
    #pragma unroll
    for (int h = 0; h < 2; ++h)
      #pragma unroll
      for (int mi = 0; mi < 2; ++mi)
        #pragma unroll
        for (int sj = 0; sj < 4; ++sj) sacc[h][mi][sj] = cinit;

    __builtin_amdgcn_s_setprio(1);
    #pragma unroll
    for (int h = 0; h < 2; ++h) {
      const char* Kb = Ks[cur] + h * 8192;
      #pragma unroll
      for (int sj = 0; sj < 4; ++sj) {
        int s = sj * 16 + lr;
        int rb = s << 7, sw = (s & 7) << 4;
        #pragma unroll
        for (int kg = 0; kg < 2; ++kg) {
          f16x8 kf = *(const f16x8*)(Kb + ((rb + (kg << 6) + (g << 4)) ^ sw));
          sacc[h][0][sj] = MFMA_F16(kf, qf[0][kg], sacc[h][0][sj]);
          sacc[h][1][sj] = MFMA_F16(kf, qf[1][kg], sacc[h][1][sj]);
        }
      }
    }
    __builtin_amdgcn_s_setprio(0);

    // per sub-tile: fixed-M softmax (native v_exp) then PV; l via ones-MFMA
    #pragma unroll
    for (int h = 0; h < 2; ++h) {
      const char* Vb = Vs + h * 8192;
      #pragma unroll
      for (int mi = 0; mi < 2; ++mi)
        #pragma unroll
        for (int sj = 0; sj < 4; ++sj) {
          sacc[h][mi][sj][0] = fexp2(sacc[h][mi][sj][0]);
          sacc[h][mi][sj][1] = fexp2(sacc[h][mi][sj][1]);
          sacc[h][mi][sj][2] = fexp2(sacc[h][mi][sj][2]);
          sacc[h][mi][sj][3] = fexp2(sacc[h][mi][sj][3]);
        }
      __builtin_amdgcn_s_setprio(1);
      #pragma unroll
      for (int t = 0; t < 2; ++t) {
        f16x8 vf[4];
        #pragma unroll
        for (int nf = 0; nf < 4; ++nf) {
          int dh = 16 * nf + lr;
          vf[nf] = *(const f16x8*)(Vb + (((dh << 7) + (t << 6) + (g << 4)) ^ ((dh & 7) << 4)));
        }
        #pragma unroll
        for (int mi = 0; mi < 2; ++mi) {
          union { unsigned int u[4]; f16x8 h; } pb;
          pb.u[0] = pkrtz(sacc[h][mi][2 * t][0], sacc[h][mi][2 * t][1]);
          pb.u[1] = pkrtz(sacc[h][mi][2 * t][2], sacc[h][mi][2 * t][3]);
          pb.u[2] = pkrtz(sacc[h][mi][2 * t + 1][0], sacc[h][mi][2 * t + 1][1]);
          pb.u[3] = pkrtz(sacc[h][mi][2 * t + 1][2], sacc[h][mi][2 * t + 1][3]);
          lacc4[mi] = MFMA_F16(ones, pb.h, lacc4[mi]);   // l[q] += sum P (matrix pipe)
          #pragma unroll
          for (int nf = 0; nf < 4; ++nf)
            oacc[mi][nf] = MFMA_F16(vf[nf], pb.h, oacc[mi][nf]);
        }
      }
      __builtin_amdgcn_s_setprio(0);
    }
  }

  // epilogue: l is lane-local (col=q), normalize, write fp16 o [8192][512]
  const int n = nh >> 3, h2 = nh & 7;
  #pragma unroll
  for (int mi = 0; mi < 2; ++mi) {
    float inv = 1.0f / lacc4[mi][0];
    int row = qt * 128 + w * 32 + 16 * mi + lr;
    _Float16* orow = o_flat + ((size_t)(n * 2048 + row)) * 512 + h2 * 64;
    #pragma unroll
    for (int nf = 0; nf < 4; ++nf) {
      u32x2 pk2;
      pk2.x = pkrtz(oacc[mi][nf][0] * inv, oacc[mi][nf][1] * inv);
      pk2.y = pkrtz(oacc[mi][nf][2] * inv, oacc[mi][nf][3] * inv);
      *(u32x2*)(orow + 16 * nf + 4 * g) = pk2;
    }
  }
}

// ---------- GEMM3: out = o @ w_proj + b (fp16 -> f32, gload_lds staging) ----------
__global__ __launch_bounds__(256, 3)
void k_gemm_proj(const _Float16* __restrict__ o_flat,
                 const _Float16* __restrict__ wpT,
                 const float* __restrict__ bias,
                 float* __restrict__ out) {
  __shared__ char As[8192], Bs[8192];
  const int tid = threadIdx.x;
  const int lane = tid & 63, w = tid >> 6;
  const int lr = lane & 15, g = lane >> 4;
  const int m0 = blockIdx.y * 128;
  const int n0 = blockIdx.x * 128;
  const int wr = w >> 1, wc = w & 1;

  const _Float16* asrc[2];
  const _Float16* bsrc[2];
  #pragma unroll
  for (int c = 0; c < 2; ++c) {
    int seg = w * 2 + c, r, ch;
    inv_swz64(seg, lane, r, ch);
    asrc[c] = o_flat + (size_t)(m0 + r) * 512 + ch * 8;
    bsrc[c] = wpT + (size_t)(n0 + r) * 512 + ch * 8;
  }

  f32x4 acc[4][4];
  #pragma unroll
  for (int i = 0; i < 4; ++i)
    #pragma unroll
    for (int j = 0; j < 4; ++j) acc[i][j] = (f32x4){0.f, 0.f, 0.f, 0.f};

  for (int kt = 0; kt < 16; ++kt) {
    const int k0 = kt * 32;
    __syncthreads();
    #pragma unroll
    for (int c = 0; c < 2; ++c) {
      gload16(asrc[c] + k0, As + (w * 2 + c) * 1024);
      gload16(bsrc[c] + k0, Bs + (w * 2 + c) * 1024);
    }
    __syncthreads();

    f16x8 af[4], bf[4];
    #pragma unroll
    for (int mi = 0; mi < 4; ++mi) {
      int r = 64 * wr + 16 * mi + lr;
      af[mi] = *(const f16x8*)(As + (((r << 6) + (g << 4)) ^ ((r & 7) << 4)));
    }
    #pragma unroll
    for (int nj = 0; nj < 4; ++nj) {
      int r = 64 * wc + 16 * nj + lr;
      bf[nj] = *(const f16x8*)(Bs + (((r << 6) + (g << 4)) ^ ((r & 7) << 4)));
    }
    __builtin_amdgcn_s_setprio(1);
    #pragma unroll
    for (int mi = 0; mi < 4; ++mi)
      #pragma unroll
      for (int nj = 0; nj < 4; ++nj)
        acc[mi][nj] = MFMA_F16(af[mi], bf[nj], acc[mi][nj]);
    __builtin_amdgcn_s_setprio(0);
  }

  #pragma unroll
  for (int mi = 0; mi < 4; ++mi) {
    int r0f = m0 + 64 * wr + 16 * mi + 4 * g;
    #pragma unroll
    for (int nj = 0; nj < 4; ++nj) {
      int c = n0 + 64 * wc + 16 * nj + lr;
      float b = bias[c];
      #pragma unroll
      for (int i = 0; i < 4; ++i)
        out[(size_t)(r0f + i) * 512 + c] = acc[mi][nj][i] + b;
    }
  }
}

extern "C" void kernel_launch(void* const* d_in, const int* in_sizes, int n_in,
                              void* d_out, int out_size, void* d_ws, size_t ws_size,
                              hipStream_t stream) {
  const float* x      = (const float*)d_in[0];
  const int*   pos_h  = (const int*)d_in[1];
  const int*   pos_w  = (const int*)d_in[2];
  const float* w_qkv  = (const float*)d_in[3];
  const float* w_proj = (const float*)d_in[4];
  const float* b_proj = (const float*)d_in[5];
  float* out = (float*)d_out;

  char* ws = (char*)d_ws;
  size_t off = 0;
  auto alloc = [&](size_t bytes) {
    char* p = ws + off;
    off += (bytes + 1023) & ~(size_t)1023;
    return p;
  };
  _Float16* xh     = (_Float16*)alloc((size_t)8192 * 512 * 2);
  _Float16* qh     = (_Float16*)alloc((size_t)32 * 2048 * 64 * 2);
  _Float16* kh     = (_Float16*)alloc((size_t)32 * 2048 * 64 * 2);
  _Float16* vT     = (_Float16*)alloc((size_t)32 * 2048 * 64 * 2);
  _Float16* o_flat = (_Float16*)alloc((size_t)8192 * 512 * 2);
  _Float16* wqT    = (_Float16*)alloc((size_t)1536 * 512 * 2);
  _Float16* wpT    = (_Float16*)alloc((size_t)512 * 512 * 2);

  hipLaunchKernelGGL(k_prep, dim3(4352), dim3(256), 0, stream,
                     x, xh, w_qkv, wqT, w_proj, wpT);
  hipLaunchKernelGGL(k_gemm_qkv, dim3(12, 64), dim3(256), 0, stream,
                     xh, wqT, pos_h, pos_w, qh, kh, vT);
  hipLaunchKernelGGL(k_attn, dim3(512), dim3(256), 0, stream, qh, kh, vT, o_flat);
  hipLaunchKernelGGL(k_gemm_proj, dim3(4, 64), dim3(256), 0, stream, o_flat, wpT, b_proj, out);
}